// Round 6
// baseline (786.336 us; speedup 1.0000x reference)
//
#include <hip/hip_runtime.h>
#include <hip/hip_bf16.h>
#include <math.h>

// Profile-HMM forward (scaled). M=4, B=64, L=512, Q=512, S=26.
//
// Round 6: round-5 (MX-fp8 K=128 scan, one barrier/step, lag-scaled gain,
// DPP transpose) with the cluster WG widened to 16 waves x 32 p-cols so the
// persistent A-fragments are 64 VGPRs/wave (round 5's 128-VGPR breg was NOT
// resident: VGPR_Count=112 => spill/remat on the serial path). 1024-thread
// block forces 4 waves/SIMD => compiler must fit <=128 VGPRs; 4x latency
// hiding vs round 5's 2 waves/SIMD.

#define MM 4
#define BB 64
#define LL 512
#define QQ 512
#define SS 26
#define ASTR 528   // albuf row stride bytes (16-mult)

typedef float f32x4 __attribute__((ext_vector_type(4)));
typedef int i32x4 __attribute__((ext_vector_type(4)));
typedef int i32x8 __attribute__((ext_vector_type(8)));

__device__ __forceinline__ float bf2f(unsigned short u) {
    return __uint_as_float(((unsigned)u) << 16);
}
__device__ __forceinline__ unsigned short f2bf(float f) {
    unsigned u = __float_as_uint(f);
    u = u + 0x7FFFu + ((u >> 16) & 1u);   // RNE
    return (unsigned short)(u >> 16);
}
__device__ __forceinline__ unsigned char f2fp8(float x) {
    int r = __builtin_amdgcn_cvt_pk_fp8_f32(x, x, 0, false);
    return (unsigned char)(r & 0xFF);
}
template<int CTRL>
__device__ __forceinline__ float qperm(float x) {
    return __int_as_float(__builtin_amdgcn_update_dpp(
        0, __float_as_int(x), CTRL, 0xF, 0xF, false));
}
// 4x4 f32 transpose across lanes (low 2 lane bits) x regs r[0..3].
__device__ __forceinline__ void tr4(float r[4], bool odd, bool bit1) {
    float t0 = qperm<0xB1>(r[0]), t1 = qperm<0xB1>(r[1]);
    float t2 = qperm<0xB1>(r[2]), t3 = qperm<0xB1>(r[3]);
    float n0 = odd ? t1 : r[0];
    float n1 = odd ? r[1] : t0;
    float n2 = odd ? t3 : r[2];
    float n3 = odd ? r[3] : t2;
    float u0 = qperm<0x4E>(n0), u1 = qperm<0x4E>(n1);
    float u2 = qperm<0x4E>(n2), u3 = qperm<0x4E>(n3);
    r[0] = bit1 ? u2 : n0;
    r[1] = bit1 ? u3 : n1;
    r[2] = bit1 ? n2 : u0;
    r[3] = bit1 ? n3 : u1;
}
__device__ __forceinline__ i32x8 ld32B(const unsigned char* p) {
    i32x4 lo = *(const i32x4*)p;
    i32x4 hi = *(const i32x4*)(p + 16);
    return __builtin_shufflevector(lo, hi, 0, 1, 2, 3, 4, 5, 6, 7);
}

// ---------------- preproc (unchanged) ----------------

__global__ void prep_small(const float* __restrict__ il, const float* __restrict__ em,
                           float* __restrict__ pi, float* __restrict__ Bem) {
    int blk = blockIdx.x;
    int m = blk / (QQ + 1);
    int r = blk % (QQ + 1);
    int lane = threadIdx.x;
    if (r < QQ) {
        float x = (lane < SS) ? em[((size_t)m * QQ + r) * SS + lane] : -1e30f;
        float mx = x;
        #pragma unroll
        for (int o = 1; o < 64; o <<= 1) mx = fmaxf(mx, __shfl_xor(mx, o));
        float e = (lane < SS) ? __expf(x - mx) : 0.f;
        float s = e;
        #pragma unroll
        for (int o = 1; o < 64; o <<= 1) s += __shfl_xor(s, o);
        if (lane < SS) Bem[((size_t)m * QQ + r) * SS + lane] = e / s;
    } else {
        float v[8];
        float mx = -1e30f;
        #pragma unroll
        for (int k = 0; k < 8; ++k) { v[k] = il[m * QQ + k * 64 + lane]; mx = fmaxf(mx, v[k]); }
        #pragma unroll
        for (int o = 1; o < 64; o <<= 1) mx = fmaxf(mx, __shfl_xor(mx, o));
        float s = 0.f;
        #pragma unroll
        for (int k = 0; k < 8; ++k) { v[k] = __expf(v[k] - mx); s += v[k]; }
        #pragma unroll
        for (int o = 1; o < 64; o <<= 1) s += __shfl_xor(s, o);
        #pragma unroll
        for (int k = 0; k < 8; ++k) pi[m * QQ + k * 64 + lane] = v[k] / s;
    }
}

__global__ void prep_arow(const float* __restrict__ Al, float* __restrict__ Lrow) {
    int row = blockIdx.x;
    int lane = threadIdx.x;
    const float* p = Al + (size_t)row * QQ;
    float v[8];
    float mx = -1e30f;
    #pragma unroll
    for (int k = 0; k < 8; ++k) { v[k] = p[k * 64 + lane]; mx = fmaxf(mx, v[k]); }
    #pragma unroll
    for (int o = 1; o < 64; o <<= 1) mx = fmaxf(mx, __shfl_xor(mx, o));
    float s = 0.f;
    #pragma unroll
    for (int k = 0; k < 8; ++k) s += __expf(v[k] - mx);
    #pragma unroll
    for (int o = 1; o < 64; o <<= 1) s += __shfl_xor(s, o);
    if (lane == 0) Lrow[row] = mx + __logf(s);
}

// Atq[m][p][q] = fp8(256 * softmax_over_p(A_logits[m][q][:])[p])  (natural q)
__global__ void prep_atq(const float* __restrict__ Al, const float* __restrict__ Lrow,
                         unsigned char* __restrict__ Atq) {
    int bid = blockIdx.x;
    int m = bid >> 3, pb = bid & 7;
    __shared__ unsigned char tile[64][68];
    int l6 = threadIdx.x & 63, g = threadIdx.x >> 6;
    for (int c = 0; c < 8; ++c) {
        #pragma unroll
        for (int r = 0; r < 16; ++r) {
            int ql = g * 16 + r;
            int q = c * 64 + ql;
            float x = Al[((size_t)m * QQ + q) * QQ + pb * 64 + l6];
            tile[ql][l6] = f2fp8(__expf(x - Lrow[m * QQ + q]) * 256.f);
        }
        __syncthreads();
        #pragma unroll
        for (int r = 0; r < 16; ++r) {
            int pr = g * 16 + r;
            Atq[((size_t)m * QQ + pb * 64 + pr) * QQ + c * 64 + l6] = tile[l6][pr];
        }
        __syncthreads();
    }
}

__global__ void prep_e(const float* __restrict__ inp, const float* __restrict__ Bem,
                       unsigned short* __restrict__ E) {
    int bid = blockIdx.x;
    int tc = bid & 7;
    int b = (bid >> 3) & 63;
    int m = bid >> 9;
    int q0 = threadIdx.x;
    float bem0[SS], bem1[SS];
    const float* bp = Bem + (size_t)m * QQ * SS;
    #pragma unroll
    for (int j = 0; j < SS; ++j) bem0[j] = bp[(size_t)q0 * SS + j];
    #pragma unroll
    for (int j = 0; j < SS; ++j) bem1[j] = bp[(size_t)(q0 + 256) * SS + j];
    const float* ip = inp + (((size_t)(m * BB + b)) * LL + tc * 64) * SS;
    for (int lt = 0; lt < 64; ++lt) {
        int t = tc * 64 + lt;
        float a0 = 0.f, a1 = 0.f;
        #pragma unroll
        for (int j = 0; j < SS; ++j) {
            float x = ip[lt * SS + j];
            a0 += x * bem0[j];
            a1 += x * bem1[j];
        }
        size_t o = (((size_t)m * LL + t) * BB + b) * QQ + q0;
        E[o] = f2bf(a0);
        E[o + 256] = f2bf(a1);
    }
}

// ---------------- scan ----------------

__launch_bounds__(1024, 4)
__global__ void hmm_scan(const unsigned short* __restrict__ E,
                         const unsigned char* __restrict__ Atq,
                         const float* __restrict__ pi,
                         float* __restrict__ out) {
    const int c = blockIdx.x;               // 16 clusters
    const int m = c >> 2, bg = c & 3;
    const int tid = threadIdx.x;
    const int lane = tid & 63;
    const int wv = tid >> 6;                // 0..15, owns p = wv*32 .. wv*32+31
    const int n16 = lane & 15;
    const int quad = lane >> 4;
    const int sl = quad * 4 + (lane & 3);   // this lane's stream (post-transpose)
    const int kk = (lane >> 2) & 3;         // p-subgroup within 16-tile
    const bool odd = (lane & 1) != 0;
    const bool bit1 = (lane & 2) != 0;
    const float LOG256 = 5.545177444479562f;

    __shared__ unsigned char albuf[2][16 * ASTR];   // [parity][s][q] fp8, natural q
    __shared__ float psl[2][16][20];                // [parity][s][wave] (pad to 80B)

    // persistent B-fragments: this wave's 32 p-columns of fp8(256*A[m]).
    // breg[h][kc] = 32 bytes (k = kc*128 + quad*32 .. +31): 64 VGPRs total.
    i32x8 breg[2][4];
    {
        const unsigned char* Ab = Atq + (size_t)m * QQ * QQ;
        #pragma unroll
        for (int h = 0; h < 2; ++h) {
            int p = wv * 32 + h * 16 + n16;
            const unsigned char* rp = Ab + (size_t)p * QQ + quad * 32;
            #pragma unroll
            for (int kc = 0; kc < 4; ++kc)
                breg[h][kc] = ld32B(rp + kc * 128);
        }
    }

    // albuf write offsets: row sl, b32 covering q = wv*32 + h*16 + kk*4 .. +3
    int wq[2];
    #pragma unroll
    for (int h = 0; h < 2; ++h)
        wq[h] = sl * ASTR + wv * 32 + h * 16 + kk * 4;

    const int b = bg * 16 + sl;
    const size_t ebase = (size_t)m * LL * BB * QQ;

    float v[2][4];
    ushort4 ea[2], eb[2];

    // prologue: prefetch e_1 -> ea ; v_0 = pi * e_0 (lambda_0 = 1)
    {
        const ushort4* E1 = (const ushort4*)(E + ebase + (size_t)1 * BB * QQ + (size_t)b * QQ);
        #pragma unroll
        for (int h = 0; h < 2; ++h) ea[h] = E1[(wv * 32 + h * 16 + kk * 4) >> 2];
        #pragma unroll
        for (int h = 0; h < 2; ++h) {
            int p0 = wv * 32 + h * 16 + kk * 4;
            f32x4 pv = *(const f32x4*)(pi + m * QQ + p0);
            ushort4 e0 = *(const ushort4*)(E + ebase + (size_t)b * QQ + p0);
            v[h][0] = pv[0] * bf2f(e0.x);
            v[h][1] = pv[1] * bf2f(e0.y);
            v[h][2] = pv[2] * bf2f(e0.z);
            v[h][3] = pv[3] * bf2f(e0.w);
        }
    }

    float lam = 1.0f;
    float ll = 0.0f;

    auto body = [&](int t, ushort4 (&ecur)[2], ushort4 (&enxt)[2]) {
        const int par = t & 1;
        // prefetch e_{t+2} (consumed next iteration)
        int tp = t + 2; if (tp > LL - 1) tp = LL - 1;
        const ushort4* Ep = (const ushort4*)(E + ebase + (size_t)tp * BB * QQ + (size_t)b * QQ);
        #pragma unroll
        for (int h = 0; h < 2; ++h) enxt[h] = Ep[(wv * 32 + h * 16 + kk * 4) >> 2];

        float g = 128.0f * __builtin_amdgcn_rcpf(lam);
        // alpha-hat_t = fp8(g * v_t), packed 4 bytes -> one b32 per h
        unsigned char* ab = &albuf[par][0];
        #pragma unroll
        for (int h = 0; h < 2; ++h) {
            int d = __builtin_amdgcn_cvt_pk_fp8_f32(g * v[h][0], g * v[h][1], 0, false);
            d = __builtin_amdgcn_cvt_pk_fp8_f32(g * v[h][2], g * v[h][3], d, true);
            *(int*)(ab + wq[h]) = d;
        }
        // partial sum for S_t (own stream sl)
        float ps = (v[0][0] + v[0][1]) + (v[0][2] + v[0][3])
                 + (v[1][0] + v[1][1]) + (v[1][2] + v[1][3]);
        ps += __shfl_xor(ps, 4);
        ps += __shfl_xor(ps, 8);
        if ((lane & 12) == 0) psl[par][sl][wv] = ps;

        ll -= __logf(g) + LOG256;   // exact: ll = log S_L - sum log(256 g_t)

        __syncthreads();

        // S_t -> lambda_{t+1} (range control only, off the MFMA critical path)
        const f32x4* pr = (const f32x4*)&psl[par][sl][0];
        f32x4 s0 = pr[0], s1 = pr[1], s2 = pr[2], s3 = pr[3];
        f32x4 ss = (s0 + s1) + (s2 + s3);
        float S = (ss[0] + ss[1]) + (ss[2] + ss[3]);
        lam = 256.0f * g * S;

        // r = alpha-hat @ A-hat : 8 MX-fp8 MFMA (K=128), 2 independent chains
        f32x4 acc[2];
        acc[0] = (f32x4){0.f, 0.f, 0.f, 0.f};
        acc[1] = (f32x4){0.f, 0.f, 0.f, 0.f};
        const unsigned char* ar = &albuf[par][0] + n16 * ASTR + quad * 32;
        #pragma unroll
        for (int kc = 0; kc < 4; ++kc) {
            i32x8 af = ld32B(ar + kc * 128);
            #pragma unroll
            for (int h = 0; h < 2; ++h)
                acc[h] = __builtin_amdgcn_mfma_scale_f32_16x16x128_f8f6f4(
                    af, breg[h][kc], acc[h], 0, 0,
                    0, 0x7F7F7F7F, 0, 0x7F7F7F7F);   // unit e8m0 scales
        }
        // transpose to (one s, 4 consecutive p) ownership, then e-multiply
        #pragma unroll
        for (int h = 0; h < 2; ++h) {
            float r[4];
            #pragma unroll
            for (int j = 0; j < 4; ++j) r[j] = acc[h][j];
            tr4(r, odd, bit1);
            v[h][0] = r[0] * bf2f(ecur[h].x);
            v[h][1] = r[1] * bf2f(ecur[h].y);
            v[h][2] = r[2] * bf2f(ecur[h].z);
            v[h][3] = r[3] * bf2f(ecur[h].w);
        }
    };

    for (int t = 0; t < LL - 2; t += 2) { body(t, ea, eb); body(t + 1, eb, ea); }
    body(LL - 2, ea, eb);

    // epilogue: S_511
    {
        float ps = (v[0][0] + v[0][1]) + (v[0][2] + v[0][3])
                 + (v[1][0] + v[1][1]) + (v[1][2] + v[1][3]);
        ps += __shfl_xor(ps, 4);
        ps += __shfl_xor(ps, 8);
        if ((lane & 12) == 0) psl[1][sl][wv] = ps;
        __syncthreads();
        const f32x4* pr = (const f32x4*)&psl[1][sl][0];
        f32x4 s0 = pr[0], s1 = pr[1], s2 = pr[2], s3 = pr[3];
        f32x4 ss = (s0 + s1) + (s2 + s3);
        float S = (ss[0] + ss[1]) + (ss[2] + ss[3]);
        ll += __logf(S);
        if (wv == 0 && (lane & 12) == 0)
            out[m * BB + bg * 16 + sl] = ll;
    }
}

// ---------------- host ----------------

extern "C" void kernel_launch(void* const* d_in, const int* in_sizes, int n_in,
                              void* d_out, int out_size, void* d_ws, size_t ws_size,
                              hipStream_t stream) {
    const float* inputs = (const float*)d_in[0];
    const float* A_logits = (const float*)d_in[1];
    const float* init_logits = (const float*)d_in[2];
    const float* em_logits = (const float*)d_in[3];
    float* out = (float*)d_out;

    char* ws = (char*)d_ws;
    size_t off = 0;
    unsigned short* E = (unsigned short*)(ws + off);  off += (size_t)MM * LL * BB * QQ * 2;  // 134 MB
    unsigned char* Atq = (unsigned char*)(ws + off);  off += (size_t)MM * QQ * QQ;           // 1 MB
    float* Bem = (float*)(ws + off);                  off += (size_t)MM * QQ * SS * 4;
    float* pi = (float*)(ws + off);                   off += (size_t)MM * QQ * 4;
    float* Lrow = (float*)(ws + off);                 off += (size_t)MM * QQ * 4;

    if (ws_size < off) {
        (void)hipMemsetAsync(d_out, 0, (size_t)out_size * sizeof(float), stream);
        return;
    }

    prep_small<<<dim3(MM * (QQ + 1)), dim3(64), 0, stream>>>(init_logits, em_logits, pi, Bem);
    prep_arow<<<dim3(MM * QQ), dim3(64), 0, stream>>>(A_logits, Lrow);
    prep_atq<<<dim3(MM * 8), dim3(256), 0, stream>>>(A_logits, Lrow, Atq);
    prep_e<<<dim3(MM * BB * 8), dim3(256), 0, stream>>>(inputs, Bem, E);
    hmm_scan<<<dim3(16), dim3(1024), 0, stream>>>(E, Atq, pi, out);
}

// Round 7
// 745.869 us; speedup vs baseline: 1.0543x; 1.0543x over previous
//
#include <hip/hip_runtime.h>
#include <hip/hip_bf16.h>
#include <math.h>

// Profile-HMM forward (scaled). M=4, B=64, L=512, Q=512, S=26.
//
// Round 7 = round 6 (16 clusters x 1024 thr, 16 waves x 32 p-cols, MX-fp8
// K=128 scan, one barrier/step) + two fixes aimed at the step skeleton:
//  1) LDS-only barrier (s_waitcnt lgkmcnt(0) + raw s_barrier): __syncthreads
//     drains vmcnt(0), exposing the e-prefetch HBM latency (~600 cyc) on the
//     serial path every step. Cross-wave data is all LDS; prefetched global
//     data is dependence-tracked to its consumer.
//  2) Hierarchical S-reduction: wave 0 publishes Sfin[16] (one b32 read per
//     lane next step) instead of every lane reading 64 B of psl. Gain becomes
//     lag-2 (lambda est. with e-mean prior); loglik bookkeeping stays exact.

#define MM 4
#define BB 64
#define LL 512
#define QQ 512
#define SS 26
#define ASTR 528   // albuf row stride bytes (16-mult)

typedef float f32x4 __attribute__((ext_vector_type(4)));
typedef int i32x4 __attribute__((ext_vector_type(4)));
typedef int i32x8 __attribute__((ext_vector_type(8)));

__device__ __forceinline__ float bf2f(unsigned short u) {
    return __uint_as_float(((unsigned)u) << 16);
}
__device__ __forceinline__ unsigned short f2bf(float f) {
    unsigned u = __float_as_uint(f);
    u = u + 0x7FFFu + ((u >> 16) & 1u);   // RNE
    return (unsigned short)(u >> 16);
}
__device__ __forceinline__ unsigned char f2fp8(float x) {
    int r = __builtin_amdgcn_cvt_pk_fp8_f32(x, x, 0, false);
    return (unsigned char)(r & 0xFF);
}
template<int CTRL>
__device__ __forceinline__ float qperm(float x) {
    return __int_as_float(__builtin_amdgcn_update_dpp(
        0, __float_as_int(x), CTRL, 0xF, 0xF, false));
}
// 4x4 f32 transpose across lanes (low 2 lane bits) x regs r[0..3].
__device__ __forceinline__ void tr4(float r[4], bool odd, bool bit1) {
    float t0 = qperm<0xB1>(r[0]), t1 = qperm<0xB1>(r[1]);
    float t2 = qperm<0xB1>(r[2]), t3 = qperm<0xB1>(r[3]);
    float n0 = odd ? t1 : r[0];
    float n1 = odd ? r[1] : t0;
    float n2 = odd ? t3 : r[2];
    float n3 = odd ? r[3] : t2;
    float u0 = qperm<0x4E>(n0), u1 = qperm<0x4E>(n1);
    float u2 = qperm<0x4E>(n2), u3 = qperm<0x4E>(n3);
    r[0] = bit1 ? u2 : n0;
    r[1] = bit1 ? u3 : n1;
    r[2] = bit1 ? n2 : u0;
    r[3] = bit1 ? n3 : u1;
}
__device__ __forceinline__ i32x8 ld32B(const unsigned char* p) {
    i32x4 lo = *(const i32x4*)p;
    i32x4 hi = *(const i32x4*)(p + 16);
    return __builtin_shufflevector(lo, hi, 0, 1, 2, 3, 4, 5, 6, 7);
}
// Barrier that waits only on LDS ops (no vmcnt drain).
// imm 0xC07F: vmcnt=63 (no wait), expcnt=7 (no wait), lgkmcnt=0 (full wait).
__device__ __forceinline__ void barrier_lds() {
    __asm__ __volatile__("" ::: "memory");
    __builtin_amdgcn_s_waitcnt(0xC07F);
    __builtin_amdgcn_s_barrier();
    __asm__ __volatile__("" ::: "memory");
}

// ---------------- preproc (unchanged) ----------------

__global__ void prep_small(const float* __restrict__ il, const float* __restrict__ em,
                           float* __restrict__ pi, float* __restrict__ Bem) {
    int blk = blockIdx.x;
    int m = blk / (QQ + 1);
    int r = blk % (QQ + 1);
    int lane = threadIdx.x;
    if (r < QQ) {
        float x = (lane < SS) ? em[((size_t)m * QQ + r) * SS + lane] : -1e30f;
        float mx = x;
        #pragma unroll
        for (int o = 1; o < 64; o <<= 1) mx = fmaxf(mx, __shfl_xor(mx, o));
        float e = (lane < SS) ? __expf(x - mx) : 0.f;
        float s = e;
        #pragma unroll
        for (int o = 1; o < 64; o <<= 1) s += __shfl_xor(s, o);
        if (lane < SS) Bem[((size_t)m * QQ + r) * SS + lane] = e / s;
    } else {
        float v[8];
        float mx = -1e30f;
        #pragma unroll
        for (int k = 0; k < 8; ++k) { v[k] = il[m * QQ + k * 64 + lane]; mx = fmaxf(mx, v[k]); }
        #pragma unroll
        for (int o = 1; o < 64; o <<= 1) mx = fmaxf(mx, __shfl_xor(mx, o));
        float s = 0.f;
        #pragma unroll
        for (int k = 0; k < 8; ++k) { v[k] = __expf(v[k] - mx); s += v[k]; }
        #pragma unroll
        for (int o = 1; o < 64; o <<= 1) s += __shfl_xor(s, o);
        #pragma unroll
        for (int k = 0; k < 8; ++k) pi[m * QQ + k * 64 + lane] = v[k] / s;
    }
}

__global__ void prep_arow(const float* __restrict__ Al, float* __restrict__ Lrow) {
    int row = blockIdx.x;
    int lane = threadIdx.x;
    const float* p = Al + (size_t)row * QQ;
    float v[8];
    float mx = -1e30f;
    #pragma unroll
    for (int k = 0; k < 8; ++k) { v[k] = p[k * 64 + lane]; mx = fmaxf(mx, v[k]); }
    #pragma unroll
    for (int o = 1; o < 64; o <<= 1) mx = fmaxf(mx, __shfl_xor(mx, o));
    float s = 0.f;
    #pragma unroll
    for (int k = 0; k < 8; ++k) s += __expf(v[k] - mx);
    #pragma unroll
    for (int o = 1; o < 64; o <<= 1) s += __shfl_xor(s, o);
    if (lane == 0) Lrow[row] = mx + __logf(s);
}

// Atq[m][p][q] = fp8(256 * softmax_over_p(A_logits[m][q][:])[p])  (natural q)
__global__ void prep_atq(const float* __restrict__ Al, const float* __restrict__ Lrow,
                         unsigned char* __restrict__ Atq) {
    int bid = blockIdx.x;
    int m = bid >> 3, pb = bid & 7;
    __shared__ unsigned char tile[64][68];
    int l6 = threadIdx.x & 63, g = threadIdx.x >> 6;
    for (int c = 0; c < 8; ++c) {
        #pragma unroll
        for (int r = 0; r < 16; ++r) {
            int ql = g * 16 + r;
            int q = c * 64 + ql;
            float x = Al[((size_t)m * QQ + q) * QQ + pb * 64 + l6];
            tile[ql][l6] = f2fp8(__expf(x - Lrow[m * QQ + q]) * 256.f);
        }
        __syncthreads();
        #pragma unroll
        for (int r = 0; r < 16; ++r) {
            int pr = g * 16 + r;
            Atq[((size_t)m * QQ + pb * 64 + pr) * QQ + c * 64 + l6] = tile[l6][pr];
        }
        __syncthreads();
    }
}

__global__ void prep_e(const float* __restrict__ inp, const float* __restrict__ Bem,
                       unsigned short* __restrict__ E) {
    int bid = blockIdx.x;
    int tc = bid & 7;
    int b = (bid >> 3) & 63;
    int m = bid >> 9;
    int q0 = threadIdx.x;
    float bem0[SS], bem1[SS];
    const float* bp = Bem + (size_t)m * QQ * SS;
    #pragma unroll
    for (int j = 0; j < SS; ++j) bem0[j] = bp[(size_t)q0 * SS + j];
    #pragma unroll
    for (int j = 0; j < SS; ++j) bem1[j] = bp[(size_t)(q0 + 256) * SS + j];
    const float* ip = inp + (((size_t)(m * BB + b)) * LL + tc * 64) * SS;
    for (int lt = 0; lt < 64; ++lt) {
        int t = tc * 64 + lt;
        float a0 = 0.f, a1 = 0.f;
        #pragma unroll
        for (int j = 0; j < SS; ++j) {
            float x = ip[lt * SS + j];
            a0 += x * bem0[j];
            a1 += x * bem1[j];
        }
        size_t o = (((size_t)m * LL + t) * BB + b) * QQ + q0;
        E[o] = f2bf(a0);
        E[o + 256] = f2bf(a1);
    }
}

// ---------------- scan ----------------

__launch_bounds__(1024, 4)
__global__ void hmm_scan(const unsigned short* __restrict__ E,
                         const unsigned char* __restrict__ Atq,
                         const float* __restrict__ pi,
                         float* __restrict__ out) {
    const int c = blockIdx.x;               // 16 clusters
    const int m = c >> 2, bg = c & 3;
    const int tid = threadIdx.x;
    const int lane = tid & 63;
    const int wv = tid >> 6;                // 0..15, owns p = wv*32 .. wv*32+31
    const int n16 = lane & 15;
    const int quad = lane >> 4;
    const int sl = quad * 4 + (lane & 3);   // this lane's stream (post-transpose)
    const int kk = (lane >> 2) & 3;         // p-subgroup within 16-tile
    const bool odd = (lane & 1) != 0;
    const bool bit1 = (lane & 2) != 0;
    const float LOG256 = 5.545177444479562f;

    __shared__ unsigned char albuf[2][16 * ASTR];   // [parity][s][q] fp8, natural q
    __shared__ float psl[2][16][20];                // [parity][s][wave] (padded)
    __shared__ float Sfin[2][16];                   // [parity][s] published S_t

    // persistent B-fragments: this wave's 32 p-columns of fp8(256*A[m]).
    i32x8 breg[2][4];
    {
        const unsigned char* Ab = Atq + (size_t)m * QQ * QQ;
        #pragma unroll
        for (int h = 0; h < 2; ++h) {
            int p = wv * 32 + h * 16 + n16;
            const unsigned char* rp = Ab + (size_t)p * QQ + quad * 32;
            #pragma unroll
            for (int kc = 0; kc < 4; ++kc)
                breg[h][kc] = ld32B(rp + kc * 128);
        }
    }

    // albuf write offsets: row sl, b32 covering q = wv*32 + h*16 + kk*4 .. +3
    int wq[2];
    #pragma unroll
    for (int h = 0; h < 2; ++h)
        wq[h] = sl * ASTR + wv * 32 + h * 16 + kk * 4;

    const int b = bg * 16 + sl;
    const size_t ebase = (size_t)m * LL * BB * QQ;

    float v[2][4];
    ushort4 ea[2], eb[2];

    // prologue: prefetch e_1 -> ea ; v_0 = pi * e_0
    {
        const ushort4* E1 = (const ushort4*)(E + ebase + (size_t)1 * BB * QQ + (size_t)b * QQ);
        #pragma unroll
        for (int h = 0; h < 2; ++h) ea[h] = E1[(wv * 32 + h * 16 + kk * 4) >> 2];
        #pragma unroll
        for (int h = 0; h < 2; ++h) {
            int p0 = wv * 32 + h * 16 + kk * 4;
            f32x4 pv = *(const f32x4*)(pi + m * QQ + p0);
            ushort4 e0 = *(const ushort4*)(E + ebase + (size_t)b * QQ + p0);
            v[h][0] = pv[0] * bf2f(e0.x);
            v[h][1] = pv[1] * bf2f(e0.y);
            v[h][2] = pv[2] * bf2f(e0.z);
            v[h][3] = pv[3] * bf2f(e0.w);
        }
    }

    // lag-2 gain state: lam targets mean quantized value ~128/512 per element.
    // S_0 per stream ~ 0.5 -> lam0 = 0.5; S_1 ~ 256*g0*S0*0.5 = 16384 -> lam1.
    float lam = 0.5f;
    float gprev = 1.0f;
    float ll = 0.0f;

    auto body = [&](int t, ushort4 (&ecur)[2], ushort4 (&enxt)[2]) {
        const int par = t & 1;
        // prefetch e_{t+2} (consumed next iteration; never force-drained)
        int tp = t + 2; if (tp > LL - 1) tp = LL - 1;
        const ushort4* Ep = (const ushort4*)(E + ebase + (size_t)tp * BB * QQ + (size_t)b * QQ);
        #pragma unroll
        for (int h = 0; h < 2; ++h) enxt[h] = Ep[(wv * 32 + h * 16 + kk * 4) >> 2];

        float g = 128.0f * __builtin_amdgcn_rcpf(lam);
        // alpha-hat_t = fp8(g * v_t), packed 4 bytes -> one b32 per h
        unsigned char* ab = &albuf[par][0];
        #pragma unroll
        for (int h = 0; h < 2; ++h) {
            int d = __builtin_amdgcn_cvt_pk_fp8_f32(g * v[h][0], g * v[h][1], 0, false);
            d = __builtin_amdgcn_cvt_pk_fp8_f32(g * v[h][2], g * v[h][3], d, true);
            *(int*)(ab + wq[h]) = d;
        }
        // per-wave partial sum for S_t (own stream sl)
        float ps = (v[0][0] + v[0][1]) + (v[0][2] + v[0][3])
                 + (v[1][0] + v[1][1]) + (v[1][2] + v[1][3]);
        ps += __shfl_xor(ps, 4);
        ps += __shfl_xor(ps, 8);
        if ((lane & 12) == 0) psl[par][sl][wv] = ps;

        ll -= __logf(g) + LOG256;   // exact: ll = log S_L - sum log(256 g_t)

        barrier_lds();              // LDS-only wait; no vmcnt drain

        // wave 0 publishes S_t for step t+1's consumers
        if (wv == 0 && lane < 16) {
            const f32x4* pr = (const f32x4*)&psl[par][lane][0];
            f32x4 s0 = pr[0], s1 = pr[1], s2 = pr[2], s3 = pr[3];
            f32x4 ss = (s0 + s1) + (s2 + s3);
            Sfin[par][lane] = (ss[0] + ss[1]) + (ss[2] + ss[3]);
        }
        // lag-2 lambda update: lam_{t+1} = 256*g_t * (256*g_{t-1}*S_{t-1}*0.5) * 0.5
        if (t == 0) {
            lam = 16384.0f;
        } else {
            float Sp = Sfin[par ^ 1][sl];   // S_{t-1}, published during body(t-1)
            lam = 16384.0f * g * gprev * Sp;
        }
        gprev = g;

        // r = alpha-hat @ A-hat : 8 MX-fp8 MFMA (K=128), 2 independent chains
        f32x4 acc[2];
        acc[0] = (f32x4){0.f, 0.f, 0.f, 0.f};
        acc[1] = (f32x4){0.f, 0.f, 0.f, 0.f};
        const unsigned char* ar = &albuf[par][0] + n16 * ASTR + quad * 32;
        #pragma unroll
        for (int kc = 0; kc < 4; ++kc) {
            i32x8 af = ld32B(ar + kc * 128);
            #pragma unroll
            for (int h = 0; h < 2; ++h)
                acc[h] = __builtin_amdgcn_mfma_scale_f32_16x16x128_f8f6f4(
                    af, breg[h][kc], acc[h], 0, 0,
                    0, 0x7F7F7F7F, 0, 0x7F7F7F7F);   // unit e8m0 scales
        }
        // transpose to (one s, 4 consecutive p) ownership, then e-multiply
        #pragma unroll
        for (int h = 0; h < 2; ++h) {
            float r[4];
            #pragma unroll
            for (int j = 0; j < 4; ++j) r[j] = acc[h][j];
            tr4(r, odd, bit1);
            v[h][0] = r[0] * bf2f(ecur[h].x);
            v[h][1] = r[1] * bf2f(ecur[h].y);
            v[h][2] = r[2] * bf2f(ecur[h].z);
            v[h][3] = r[3] * bf2f(ecur[h].w);
        }
    };

    for (int t = 0; t < LL - 2; t += 2) { body(t, ea, eb); body(t + 1, eb, ea); }
    body(LL - 2, ea, eb);

    // epilogue: exact S_511 (full reduction; one heavyweight barrier is fine)
    {
        float ps = (v[0][0] + v[0][1]) + (v[0][2] + v[0][3])
                 + (v[1][0] + v[1][1]) + (v[1][2] + v[1][3]);
        ps += __shfl_xor(ps, 4);
        ps += __shfl_xor(ps, 8);
        if ((lane & 12) == 0) psl[1][sl][wv] = ps;
        __syncthreads();
        const f32x4* pr = (const f32x4*)&psl[1][sl][0];
        f32x4 s0 = pr[0], s1 = pr[1], s2 = pr[2], s3 = pr[3];
        f32x4 ss = (s0 + s1) + (s2 + s3);
        float S = (ss[0] + ss[1]) + (ss[2] + ss[3]);
        ll += __logf(S);
        if (wv == 0 && (lane & 12) == 0)
            out[m * BB + bg * 16 + sl] = ll;
    }
}

// ---------------- host ----------------

extern "C" void kernel_launch(void* const* d_in, const int* in_sizes, int n_in,
                              void* d_out, int out_size, void* d_ws, size_t ws_size,
                              hipStream_t stream) {
    const float* inputs = (const float*)d_in[0];
    const float* A_logits = (const float*)d_in[1];
    const float* init_logits = (const float*)d_in[2];
    const float* em_logits = (const float*)d_in[3];
    float* out = (float*)d_out;

    char* ws = (char*)d_ws;
    size_t off = 0;
    unsigned short* E = (unsigned short*)(ws + off);  off += (size_t)MM * LL * BB * QQ * 2;  // 134 MB
    unsigned char* Atq = (unsigned char*)(ws + off);  off += (size_t)MM * QQ * QQ;           // 1 MB
    float* Bem = (float*)(ws + off);                  off += (size_t)MM * QQ * SS * 4;
    float* pi = (float*)(ws + off);                   off += (size_t)MM * QQ * 4;
    float* Lrow = (float*)(ws + off);                 off += (size_t)MM * QQ * 4;

    if (ws_size < off) {
        (void)hipMemsetAsync(d_out, 0, (size_t)out_size * sizeof(float), stream);
        return;
    }

    prep_small<<<dim3(MM * (QQ + 1)), dim3(64), 0, stream>>>(init_logits, em_logits, pi, Bem);
    prep_arow<<<dim3(MM * QQ), dim3(64), 0, stream>>>(A_logits, Lrow);
    prep_atq<<<dim3(MM * 8), dim3(256), 0, stream>>>(A_logits, Lrow, Atq);
    prep_e<<<dim3(MM * BB * 8), dim3(256), 0, stream>>>(inputs, Bem, E);
    hmm_scan<<<dim3(16), dim3(1024), 0, stream>>>(E, Atq, pi, out);
}